// Round 4
// baseline (904.726 us; speedup 1.0000x reference)
//
#include <hip/hip_runtime.h>
#include <math.h>

// TransformerLayer fused implementation for MI355X (gfx950).
// Reference quirks kept faithful:
//  - v / attended_values are DEAD code in the reference -> Wv never touched.
//  - scores scaled by 1/sqrt(D)=1/sqrt(2048), not 1/sqrt(head_dim).
//  - x2 = LN1(x) + x  (residual added to LN output).
// Outputs (concat in d_out): out [4,1024,2048] fp32, attn_probs [4,32,1024,1024] fp32.
//
// R4 changes: launch-graph re-pack, 5 -> 3 launches exploiting the independent
// chains {QK gemm -> attn} and {FF1 -> FF2}:
//  - gemm2: QK projection (1024 blks) + FF1 (512 blks), one launch, 2:1 interleave.
//  - attn_ff2: attn (8192 blks, HBM-write-bound) + FF2 (512 blks, MFMA-bound),
//    FF2 every 17th block so it executes under attn's idle MFMA pipe.
//  - FF2 'out' stores non-temporal (written once, never re-read).

typedef unsigned short u16;
typedef u16    u16x4  __attribute__((ext_vector_type(4)));
typedef u16    u16x8  __attribute__((ext_vector_type(8)));
typedef __bf16 bf16x8 __attribute__((ext_vector_type(8)));
typedef float  f32x4  __attribute__((ext_vector_type(4)));

#define MFMA16(a, b, c) __builtin_amdgcn_mfma_f32_16x16x32_bf16((a), (b), (c), 0, 0, 0)

__device__ __forceinline__ u16 f2bf(float f) {
  unsigned u = __builtin_bit_cast(unsigned, f);
  u += 0x7fffu + ((u >> 16) & 1u);   // RNE
  return (u16)(u >> 16);
}

// global -> LDS direct copy, 16 B per lane. LDS dest must be wave-uniform;
// HW writes ldsbase + lane*16.
__device__ __forceinline__ void gload_lds16(const u16* g, u16* l) {
  __builtin_amdgcn_global_load_lds(
      (const __attribute__((address_space(1))) unsigned int*)g,
      (__attribute__((address_space(3))) unsigned int*)l, 16, 0, 0);
}

__device__ __forceinline__ void nt_store4(float* p, f32x4 v) {
  __builtin_nontemporal_store(v, (f32x4*)p);
}

// ---------------------------------------------------------------------------
// Prep kernel: blocks [0,4096) transpose+cast the 4 weights; blocks
// [4096,5120) run the fused LN pipeline (independent work, one launch).
// ---------------------------------------------------------------------------
__global__ __launch_bounds__(256) void prep_kernel(
    const float* __restrict__ W0, const float* __restrict__ W1,
    const float* __restrict__ W2, const float* __restrict__ W3,
    u16* __restrict__ dst,
    const float* __restrict__ x,
    const float* __restrict__ s1, const float* __restrict__ b1,
    const float* __restrict__ s2, const float* __restrict__ b2,
    u16* __restrict__ h_bf, float* __restrict__ x2o, u16* __restrict__ h2_bf) {
  __shared__ u16 tile[64][65];
  const int bx = blockIdx.x;
  if (bx < 4096) {
    // ---- weight transpose + fp32->bf16 cast: W[K][N] -> WT[N][K] ----
    const int z = bx >> 10, rem = bx & 1023;
    const float* W = (z == 0) ? W0 : (z == 1) ? W1 : (z == 2) ? W2 : W3;
    u16* WT = dst + (size_t)z * 2048 * 2048;
    const int n0 = (rem & 31) * 64, k0 = (rem >> 5) * 64;
    const int c = threadIdx.x & 63, rb = threadIdx.x >> 6;
#pragma unroll
    for (int i = 0; i < 16; i++) {
      int r = rb + i * 4;
      tile[r][c] = f2bf(W[(size_t)(k0 + r) * 2048 + n0 + c]);
    }
    __syncthreads();
#pragma unroll
    for (int i = 0; i < 16; i++) {
      int r = rb + i * 4;
      WT[(size_t)(n0 + r) * 2048 + k0 + c] = tile[c][r];
    }
    return;
  }

  // ---- h = LN1(x); x2 = h + x; h2 = LN2(x2). One wave per row. ----
  const int wid = threadIdx.x >> 6, lane = threadIdx.x & 63;
  const size_t rbase = (size_t)((bx - 4096) * 4 + wid) * 2048;

  float v[32];
#pragma unroll
  for (int i = 0; i < 8; i++)
    *(float4*)&v[i * 4] = *(const float4*)(x + rbase + i * 256 + lane * 4);

  float s = 0.f;
#pragma unroll
  for (int i = 0; i < 32; i++) s += v[i];
#pragma unroll
  for (int off = 32; off; off >>= 1) s += __shfl_xor(s, off, 64);
  const float m1 = s * (1.f / 2048.f);

  float ss = 0.f;
#pragma unroll
  for (int i = 0; i < 32; i++) { float d = v[i] - m1; ss += d * d; }
#pragma unroll
  for (int off = 32; off; off >>= 1) ss += __shfl_xor(ss, off, 64);
  const float r1 = rsqrtf(ss * (1.f / 2048.f) + 1e-5f);

  float xx[32];
#pragma unroll
  for (int i = 0; i < 8; i++) {
    const int c = i * 256 + lane * 4;
    float4 w4 = *(const float4*)(s1 + c);
    float4 b4 = *(const float4*)(b1 + c);
    u16x4 hv;
#pragma unroll
    for (int j = 0; j < 4; j++) {
      float hh = (v[i * 4 + j] - m1) * r1 * (&w4.x)[j] + (&b4.x)[j];
      xx[i * 4 + j] = hh + v[i * 4 + j];
      hv[j] = f2bf(hh);
    }
    *(u16x4*)(h_bf + rbase + c) = hv;
    *(float4*)(x2o + rbase + c) = *(float4*)&xx[i * 4];
  }

  s = 0.f;
#pragma unroll
  for (int i = 0; i < 32; i++) s += xx[i];
#pragma unroll
  for (int off = 32; off; off >>= 1) s += __shfl_xor(s, off, 64);
  const float m2 = s * (1.f / 2048.f);

  ss = 0.f;
#pragma unroll
  for (int i = 0; i < 32; i++) { float d = xx[i] - m2; ss += d * d; }
#pragma unroll
  for (int off = 32; off; off >>= 1) ss += __shfl_xor(ss, off, 64);
  const float r2 = rsqrtf(ss * (1.f / 2048.f) + 1e-5f);

#pragma unroll
  for (int i = 0; i < 8; i++) {
    const int c = i * 256 + lane * 4;
    float4 w4 = *(const float4*)(s2 + c);
    float4 b4 = *(const float4*)(b2 + c);
    u16x4 hv;
#pragma unroll
    for (int j = 0; j < 4; j++)
      hv[j] = f2bf((xx[i * 4 + j] - m2) * r2 * (&w4.x)[j] + (&b4.x)[j]);
    *(u16x4*)(h2_bf + rbase + c) = hv;
  }
}

// ---------------------------------------------------------------------------
// bf16 MFMA GEMM body (m97 structure): C tile [128x128] of
// C[M][N] = A[M][2048] @ BT[N][2048]^T.  BK=64, global_load_lds dwordx4
// staging, 4 waves x (4x4) 16x16x32 MFMA tiles, 2-barrier K-loop.
// NTOUT: use non-temporal stores for the fp32 output path.
// ---------------------------------------------------------------------------
template <int N, int BIAS, int RELU, int RESID, int OUTBF, int NTOUT>
__device__ __forceinline__ void gemm_body(
    const u16* __restrict__ A, const u16* __restrict__ BT,
    const float* __restrict__ bias, const float* __restrict__ resid,
    void* __restrict__ Cout, const int row0, const int col0,
    u16* __restrict__ As, u16* __restrict__ Bs) {
  constexpr int K = 2048, BK = 64;
  const int tid = threadIdx.x;
  const int wid = tid >> 6, lane = tid & 63, lr = lane & 15, quad = lane >> 4;
  const int wr0 = (wid >> 1) * 64, wc0 = (wid & 1) * 64;
  const int srow = lane >> 3;           // 0..7 row within 8-row group
  const int scol = (lane & 7) * 8;      // u16 col within BK

  f32x4 acc[4][4];
#pragma unroll
  for (int i = 0; i < 4; i++)
#pragma unroll
    for (int j = 0; j < 4; j++) acc[i][j] = (f32x4){0.f, 0.f, 0.f, 0.f};

  const u16* gA = A + (size_t)(row0 + srow) * K + scol;
  const u16* gB = BT + (size_t)(col0 + srow) * K + scol;

  for (int k0 = 0; k0 < K; k0 += BK) {
    if (k0) __syncthreads();   // previous compute done before LDS overwrite
#pragma unroll
    for (int i = 0; i < 4; i++) {
      const int rg = i * 32 + wid * 8;              // wave-uniform row group
      gload_lds16(gA + (size_t)rg * K + k0, &As[rg * BK]);
      gload_lds16(gB + (size_t)rg * K + k0, &Bs[rg * BK]);
    }
    __syncthreads();           // compiler drains vmcnt(0) before s_barrier

#pragma unroll
    for (int kk = 0; kk < 2; kk++) {
      bf16x8 af[4], bfr[4];
#pragma unroll
      for (int i = 0; i < 4; i++)
        af[i] = *(const bf16x8*)&As[(wr0 + i * 16 + lr) * BK + kk * 32 + quad * 8];
#pragma unroll
      for (int j = 0; j < 4; j++)
        bfr[j] = *(const bf16x8*)&Bs[(wc0 + j * 16 + lr) * BK + kk * 32 + quad * 8];
#pragma unroll
      for (int i = 0; i < 4; i++)
#pragma unroll
        for (int j = 0; j < 4; j++) acc[i][j] = MFMA16(af[i], bfr[j], acc[i][j]);
    }
  }

  // epilogue: C row = quad*4 + reg, col = lane&15 (verified gfx950 C/D layout)
#pragma unroll
  for (int i = 0; i < 4; i++) {
#pragma unroll
    for (int r = 0; r < 4; r++) {
      const int row = row0 + wr0 + i * 16 + quad * 4 + r;
#pragma unroll
      for (int j = 0; j < 4; j++) {
        const int col = col0 + wc0 + j * 16 + lr;
        float v = acc[i][j][r];
        if (BIAS) v += bias[col];
        if (RELU) v = fmaxf(v, 0.f);
        if (RESID) v += resid[(size_t)row * N + col];
        if (OUTBF) {
          ((u16*)Cout)[(size_t)row * N + col] = f2bf(v);
        } else if (NTOUT) {
          __builtin_nontemporal_store(v, (float*)Cout + (size_t)row * N + col);
        } else {
          ((float*)Cout)[(size_t)row * N + col] = v;
        }
      }
    }
  }
}

// ---------------------------------------------------------------------------
// Launch 2: QK projection (1024 blocks) + FF1 (512 blocks), 2:1 interleaved.
// ---------------------------------------------------------------------------
__global__ __launch_bounds__(256) void gemm2_kernel(
    const u16* __restrict__ h_bf, const u16* __restrict__ WqkT,
    const u16* __restrict__ h2_bf, const u16* __restrict__ F1T,
    const float* __restrict__ f1b,
    u16* __restrict__ qk_bf, u16* __restrict__ a1_bf) {
  __shared__ u16 As[128 * 64];
  __shared__ u16 Bs[128 * 64];
  const int bx = blockIdx.x;
  const int g = bx / 3, r = bx - g * 3;
  if (r < 2) {
    const int idx = g * 2 + r;                    // [0,1024): QK, grid 32x32
    gemm_body<4096, 0, 0, 0, 1, 0>(h_bf, WqkT, nullptr, nullptr, qk_bf,
                                   (idx >> 5) * 128, (idx & 31) * 128, As, Bs);
  } else {
    gemm_body<2048, 1, 1, 0, 1, 0>(h2_bf, F1T, f1b, nullptr, a1_bf,
                                   (g >> 4) * 128, (g & 15) * 128, As, Bs);
  }
}

// ---------------------------------------------------------------------------
// attn body: scores + softmax for one (b, h, 16 q-rows) tile.
// scores[16][1024] in LDS, XOR-swizzled at 16-float-chunk granularity
// (physical chunk = logical chunk ^ ((row>>2)&1)): 4-way -> 2-way (free).
// probs written exactly once -> non-temporal float4 stores.
// qk layout: [B*S][4096], q at col h*64, k at col 2048 + h*64 (merged GEMM).
// ---------------------------------------------------------------------------
__device__ __forceinline__ void attn_body(const u16* __restrict__ qk,
                                          float* __restrict__ probs,
                                          const int idx, float* __restrict__ sc) {
  const int tid = threadIdx.x, wid = tid >> 6, lane = tid & 63;
  const int lr = lane & 15, quad = lane >> 4;
  const int q0 = (idx & 63) * 16, h = (idx >> 6) & 31, b = idx >> 11;

  const size_t qbase = (size_t)(b * 1024 + q0 + lr) * 4096 + h * 64 + quad * 8;
  const bf16x8 a0 = *(const bf16x8*)(qk + qbase);
  const bf16x8 a1 = *(const bf16x8*)(qk + qbase + 32);
  const float scale = 0.022097086912079608f;  // 1/sqrt(2048)

  const int ssw = quad & 1;  // store-side swizzle bit ((row>>2)&1, row=quad*4+r)
  for (int t = 0; t < 16; t++) {
    const int c0 = wid * 256 + t * 16;
    const size_t kbase = (size_t)(b * 1024 + c0 + lr) * 4096 + 2048 + h * 64 + quad * 8;
    const bf16x8 b0 = *(const bf16x8*)(qk + kbase);
    const bf16x8 b1 = *(const bf16x8*)(qk + kbase + 32);
    f32x4 acc = (f32x4){0.f, 0.f, 0.f, 0.f};
    acc = MFMA16(a0, b0, acc);
    acc = MFMA16(a1, b1, acc);
    const int pc = ((wid * 16 + t) ^ ssw) * 16 + lr;  // physical col
#pragma unroll
    for (int r = 0; r < 4; r++) sc[(quad * 4 + r) * 1024 + pc] = acc[r] * scale;
  }
  __syncthreads();

  // softmax, float4-vectorized; lane handles logical cols {i*256 + lane*4 + 0..3}
  const int rsw = wid & 1;  // read-side swizzle bit ((row>>2)&1, row=wid*4+rr)
#pragma unroll
  for (int rr = 0; rr < 4; rr++) {
    const int row = wid * 4 + rr;
    float vals[16];
#pragma unroll
    for (int i = 0; i < 4; i++) {
      const int pidx = (i * 16 + ((lane >> 2) ^ rsw)) * 16 + (lane & 3) * 4;
      *(f32x4*)&vals[i * 4] = *(const f32x4*)&sc[row * 1024 + pidx];
    }
    float mx = -1e30f;
#pragma unroll
    for (int i = 0; i < 16; i++) mx = fmaxf(mx, vals[i]);
#pragma unroll
    for (int off = 32; off; off >>= 1) mx = fmaxf(mx, __shfl_xor(mx, off, 64));
    float sum = 0.f;
#pragma unroll
    for (int i = 0; i < 16; i++) {
      vals[i] = __expf(vals[i] - mx);
      sum += vals[i];
    }
#pragma unroll
    for (int off = 32; off; off >>= 1) sum += __shfl_xor(sum, off, 64);
    const float inv = 1.f / sum;
    float* pr = probs + (size_t)((b * 32 + h) * 1024 + q0 + row) * 1024;
#pragma unroll
    for (int i = 0; i < 4; i++) {
      f32x4 o;
#pragma unroll
      for (int j = 0; j < 4; j++) o[j] = vals[i * 4 + j] * inv;
      nt_store4(&pr[i * 256 + lane * 4], o);
    }
  }
}

// ---------------------------------------------------------------------------
// Launch 3: attn (8192 blocks, HBM-write-bound) + FF2 (512 blocks, MFMA-bound).
// 8704 = 512*17 blocks; every 17th (r==8) is an FF2 block so it co-runs under
// attn's idle MFMA/VALU pipes.
// ---------------------------------------------------------------------------
__global__ __launch_bounds__(256) void attn_ff2_kernel(
    const u16* __restrict__ qk, float* __restrict__ probs,
    const u16* __restrict__ a1, const u16* __restrict__ F2T,
    const float* __restrict__ f2b, const float* __restrict__ x2,
    float* __restrict__ out) {
  __shared__ char smem[65536];  // attn: 64KB f32 sc; gemm: 2x16KB u16 tiles
  const int bx = blockIdx.x;
  const int g = bx / 17, r = bx - g * 17;
  if (r == 8) {
    u16* As = (u16*)smem;
    u16* Bs = (u16*)(smem + 32768);
    gemm_body<2048, 1, 0, 1, 0, 1>(a1, F2T, f2b, x2, out,
                                   (g >> 4) * 128, (g & 15) * 128, As, Bs);
  } else {
    const int idx = g * 16 + (r < 8 ? r : r - 1);
    attn_body(qk, probs, idx, (float*)smem);
  }
}

// ---------------------------------------------------------------------------
extern "C" void kernel_launch(void* const* d_in, const int* in_sizes, int n_in,
                              void* d_out, int out_size, void* d_ws, size_t ws_size,
                              hipStream_t stream) {
  const float* x = (const float*)d_in[0];
  const float* Wq = (const float*)d_in[1];
  const float* Wk = (const float*)d_in[2];
  // d_in[3] = Wv: dead in the reference (attended values are discarded)
  const float* ln1s = (const float*)d_in[4];
  const float* ln1b = (const float*)d_in[5];
  const float* ln2s = (const float*)d_in[6];
  const float* ln2b = (const float*)d_in[7];
  const float* f1w = (const float*)d_in[8];
  const float* f1b = (const float*)d_in[9];
  const float* f2w = (const float*)d_in[10];
  const float* f2b = (const float*)d_in[11];

  char* p = (char*)d_ws;
  const size_t WSZ = (size_t)2048 * 2048 * 2;   // 8 MB bf16 weight
  const size_t ASZ = (size_t)4096 * 2048 * 2;   // 16 MB bf16 activation
  u16* WqkT = (u16*)p; p += 2 * WSZ;            // [WqT; WkT] contiguous, 4096 rows
  u16* F1T = (u16*)p; p += WSZ;
  u16* F2T = (u16*)p; p += WSZ;
  u16* h_bf = (u16*)p; p += ASZ;
  u16* h2_bf = (u16*)p; p += ASZ;
  u16* qk_bf = (u16*)p; p += 2 * ASZ;           // [4096][4096] merged Q|K
  u16* a1_bf = (u16*)p; p += ASZ;
  float* x2 = (float*)p; p += (size_t)4096 * 2048 * 4;

  float* out = (float*)d_out;
  float* probs = out + (size_t)4096 * 2048;

  // launch 1: transposes (blocks 0..4095) + LN pipeline (4096..5119)
  prep_kernel<<<5120, 256, 0, stream>>>(Wq, Wk, f1w, f2w, WqkT,
                                        x, ln1s, ln1b, ln2s, ln2b,
                                        h_bf, x2, h2_bf);

  // launch 2: QK projection + FF1, interleaved
  gemm2_kernel<<<1536, 256, 0, stream>>>(h_bf, WqkT, h2_bf, F1T, f1b,
                                         qk_bf, a1_bf);

  // launch 3: attn + FF2, interleaved
  attn_ff2_kernel<<<8704, 256, 0, stream>>>(qk_bf, probs, a1_bf, F2T, f2b,
                                            x2, out);
}